// Round 9
// baseline (458.881 us; speedup 1.0000x reference)
//
#include <hip/hip_runtime.h>
#include <math.h>

#define NUM_NODES 94
#define SEQ_LEN 784
#define OUT_CLASSES 10
#define EPB 32              // 2 independent chains x 16 elements
#define SP 396              // staged-input LDS stride (f32): 2-way max (free)
#define THALF 392           // input staged in two halves
#define YP 104              // y stride per element (f16), R4/R8-verified skew
#define TEAMSZ 1664         // 16 * YP f16 units per team buffer

#define TWO_GAMMA 0.2f
#define OM2 0.0503551324598949f            // (2*pi/28)^2
#define INV_SQRT_N 0.103142124625879       // 1/sqrt(94)
#define LOG2E 1.4426950408889634
// exp2 arg = 2A*log2e -> fold 2*INV_SQRT_N*LOG2E into W, w_ih, bias (K-slots)
#define WSCALE ((float)(2.0 * INV_SQRT_N * LOG2E))

typedef _Float16 half8 __attribute__((ext_vector_type(8)));
typedef _Float16 half4 __attribute__((ext_vector_type(4)));
typedef _Float16 half2v __attribute__((ext_vector_type(2)));
typedef float    floatx4 __attribute__((ext_vector_type(4)));
typedef float    f2 __attribute__((ext_vector_type(2)));

// R9: PHASE-SHIFTED DUAL-CHAIN. Team A (waves 0-3) and team B (waves 4-7)
// each own an independent 16-element recurrence, offset by half a step.
// Every barrier phase pairs, on each SIMD, one P0 wave (read y + 6 MFMA,
// stall-heavy) with one P1 wave (12 trans dynamics + publish, issue-heavy):
// P0's LDS/MFMA latency hides under P1's trans issue and vice versa.
// R8 proved co-resident SAME-phase waves hide nothing (742 cy); this is the
// same resources with phase diversity. Per team: R8's balanced 1.5-tile
// split (own tile ww + parity-half of tile 4+(ww>>1)); K=96 folding (rows
// 94=s_t, 95=1.0); skewed b64 layout; ONE y buffer per team (WAR separated
// by the phase barrier); D fragments persist in registers across barriers.
__global__
__attribute__((amdgpu_flat_work_group_size(512, 512)))
void horn_kernel(
    const float* __restrict__ input,   // (1024, 784)
    const float* __restrict__ w_ih,    // (94, 1)
    const float* __restrict__ b_ih,    // (94)
    const float* __restrict__ w_hh,    // (94, 94)
    const float* __restrict__ b_hh,    // (94)
    const float* __restrict__ w_ro,    // (10, 94)
    const float* __restrict__ b_ro,    // (10)
    float* __restrict__ out)           // (1024, 10)
{
    __shared__ __align__(16) float    sinl[EPB * SP];    // 50,688 B (reused as xsh)
    __shared__ __align__(16) _Float16 ybuf[2 * TEAMSZ];  //  6,656 B (total 57,344)

    const int tid  = threadIdx.x;
    const int w    = tid >> 6;         // wave 0..7
    const int lane = tid & 63;
    const int e    = lane & 15;        // element-in-chain (B/D col); A row-in-tile
    const int h    = lane >> 4;        // 0..3 (k-group / D row-group)
    const int bb   = blockIdx.x;

    const int  team = w >> 2;          // 0 = chain A, 1 = chain B
    const int  ww   = w & 3;           // wave-in-team: own tile ww
    const int  S    = 4 + (ww >> 1);   // shared tile (4 or 5)
    const int  p    = ww & 1;          // parity: shared D rows 4h+2p, 4h+2p+1
    const bool duty = (ww == 3 && h == 3);   // shared rows 94,95 = input slots

    const int Eloc = 16 * team + e;    // element within block
    _Float16* ybT  = ybuf + team * TEAMSZ;
    const int eoff = 104 * e + 4 * (e >> 3);   // skewed element base (f16 units)

    // ---- stage input half 0 + zero y buffers ----
    {
        const float* src = input + (size_t)bb * EPB * SEQ_LEN;
        for (int idx = tid; idx < EPB * (THALF / 4); idx += 512) {
            int ee = idx / (THALF / 4);
            int cc = idx - ee * (THALF / 4);
            *(floatx4*)&sinl[ee * SP + 4 * cc] =
                *(const floatx4*)(src + (size_t)ee * SEQ_LEN + 4 * cc);
        }
    }
    for (int i = tid; i < (2 * TEAMSZ) / 2; i += 512) ((float*)ybuf)[i] = 0.0f;
    __syncthreads();
    // ---- seed slots: row 94 = s_0, row 95 = 1.0 (both teams) ----
    if (tid < EPB) {
        const int tm = tid >> 4, ee = tid & 15;
        const int eo = 104 * ee + 4 * (ee >> 3);
        const float s0 = sinl[tid * SP];
        half2v v; v[0] = (_Float16)s0; v[1] = (_Float16)1.0f;
        *(half2v*)&ybuf[tm * TEAMSZ + eo + NUM_NODES] = v;
    }

    // ---- A fragments: own tile ww + shared tile S; K-cols 94/95 = w_ih/bias ----
    #define LOAD_A(ROW, A0, A1, A2) do {                                           \
        const int arow = (ROW);                                                    \
        _Pragma("unroll")                                                          \
        for (int i = 0; i < 8; ++i) {                                              \
            const int k = 8 * h + i;                                               \
            float v0 = 0.0f, v1 = 0.0f, v2 = 0.0f;                                 \
            if (arow < NUM_NODES) {                                                \
                v0 = w_hh[arow * NUM_NODES + k] * WSCALE;                          \
                v1 = w_hh[arow * NUM_NODES + k + 32] * WSCALE;                     \
                const int k2 = k + 64;                                             \
                if      (k2 <  NUM_NODES) v2 = w_hh[arow * NUM_NODES + k2] * WSCALE; \
                else if (k2 == NUM_NODES) v2 = w_ih[arow] * WSCALE;                \
                else                      v2 = (b_ih[arow] + b_hh[arow]) * WSCALE; \
            }                                                                      \
            (A0)[i] = (_Float16)v0; (A1)[i] = (_Float16)v1; (A2)[i] = (_Float16)v2;\
        }                                                                          \
    } while (0)

    half8 AO0, AO1, AO2, AS0, AS1, AS2;
    LOAD_A(16 * ww + e, AO0, AO1, AO2);
    LOAD_A(16 * S + e,  AS0, AS1, AS2);
    #undef LOAD_A

    // ---- per-lane state: own rows 16ww+4h+{0..3}; shared rows 16S+4h+2p+{0,1} ----
    f2 x01 = {0,0}, x23 = {0,0}, y01 = {0,0}, y23 = {0,0};
    f2 xs  = {0,0}, ys  = {0,0};

    const f2 no2 = {-OM2, -OM2};
    const f2 p82 = {1.0f - TWO_GAMMA, 1.0f - TWO_GAMMA};   // 0.8
    const f2 h05 = {0.5f, 0.5f};
    const floatx4 zf4 = {0,0,0,0};
    floatx4 dO = zf4, dS = zf4;        // persist across the phase barrier

    // P0: read y, 6 MFMA (own + shared), keep D in registers.
    #define P0() do {                                                              \
        const _Float16* yb = &ybT[eoff + 8 * h];                                   \
        half4 l0 = *(const half4*)(yb);      half4 u0 = *(const half4*)(yb + 4);   \
        half4 l1 = *(const half4*)(yb + 32); half4 u1 = *(const half4*)(yb + 36);  \
        half4 l2 = *(const half4*)(yb + 64); half4 u2 = *(const half4*)(yb + 68);  \
        half8 B0 = __builtin_shufflevector(l0, u0, 0, 1, 2, 3, 4, 5, 6, 7);        \
        half8 B1 = __builtin_shufflevector(l1, u1, 0, 1, 2, 3, 4, 5, 6, 7);        \
        half8 B2 = __builtin_shufflevector(l2, u2, 0, 1, 2, 3, 4, 5, 6, 7);        \
        floatx4 a_ = __builtin_amdgcn_mfma_f32_16x16x32_f16(AO0, B0, zf4, 0, 0, 0);\
        floatx4 b_ = __builtin_amdgcn_mfma_f32_16x16x32_f16(AO1, B1, zf4, 0, 0, 0);\
        a_ = __builtin_amdgcn_mfma_f32_16x16x32_f16(AO2, B2, a_, 0, 0, 0);         \
        dO = a_ + b_;                                                              \
        floatx4 c_ = __builtin_amdgcn_mfma_f32_16x16x32_f16(AS0, B0, zf4, 0, 0, 0);\
        floatx4 d_ = __builtin_amdgcn_mfma_f32_16x16x32_f16(AS1, B1, zf4, 0, 0, 0);\
        c_ = __builtin_amdgcn_mfma_f32_16x16x32_f16(AS2, B2, c_, 0, 0, 0);         \
        dS = c_ + d_;                                                              \
    } while (0)

    // P1: dynamics (6 nodes: 4 own + 2 shared), publish y(t+1) + s-slot.
    #define P1(TL, TT) do {                                                        \
        f2 q0 = no2 * x01 + h05;  q0 = p82 * y01 + q0;                             \
        f2 q1 = no2 * x23 + h05;  q1 = p82 * y23 + q1;                             \
        f2 qs = no2 * xs  + h05;  qs = p82 * ys  + qs;                             \
        x01 += y01;  x23 += y23;  xs += ys;                                        \
        float sn = 0.0f;                                                           \
        if (duty) {                                                                \
            const int tloc = (TL) + 1;                                             \
            if (tloc < THALF) sn = sinl[Eloc * SP + tloc];                         \
            else {                                                                 \
                const int tg = ((TT) + 1 < SEQ_LEN) ? (TT) + 1 : (SEQ_LEN - 1);    \
                sn = input[((size_t)bb * EPB + Eloc) * SEQ_LEN + tg];              \
            }                                                                      \
        }                                                                          \
        f2 dsv;                                                                    \
        dsv[0] = p ? dS[2] : dS[0];  dsv[1] = p ? dS[3] : dS[1];                   \
        f2 r0, r1, rs;                                                             \
        r0[0] = __builtin_amdgcn_rcpf(__builtin_amdgcn_exp2f(dO[0]) + 1.0f);       \
        r0[1] = __builtin_amdgcn_rcpf(__builtin_amdgcn_exp2f(dO[1]) + 1.0f);       \
        r1[0] = __builtin_amdgcn_rcpf(__builtin_amdgcn_exp2f(dO[2]) + 1.0f);       \
        r1[1] = __builtin_amdgcn_rcpf(__builtin_amdgcn_exp2f(dO[3]) + 1.0f);       \
        rs[0] = __builtin_amdgcn_rcpf(__builtin_amdgcn_exp2f(dsv[0]) + 1.0f);      \
        rs[1] = __builtin_amdgcn_rcpf(__builtin_amdgcn_exp2f(dsv[1]) + 1.0f);      \
        y01 = q0 - r0;  y23 = q1 - r1;  ys = qs - rs;                              \
        half4 yh;                                                                  \
        yh[0] = (_Float16)y01[0]; yh[1] = (_Float16)y01[1];                        \
        yh[2] = (_Float16)y23[0]; yh[3] = (_Float16)y23[1];                        \
        *(half4*)&ybT[eoff + 16 * ww + 4 * h] = yh;                                \
        if (duty) {                                                                \
            half2v sv; sv[0] = (_Float16)sn; sv[1] = (_Float16)1.0f;               \
            *(half2v*)&ybT[eoff + NUM_NODES] = sv;                                 \
        } else {                                                                   \
            half2v s2; s2[0] = (_Float16)ys[0]; s2[1] = (_Float16)ys[1];           \
            *(half2v*)&ybT[eoff + 16 * S + 4 * h + 2 * p] = s2;                    \
        }                                                                          \
    } while (0)

    __syncthreads();                   // staging + seeding visible
    if (team == 1) { P0(); }           // B leads by half a step
    __syncthreads();

    for (int hf = 0; hf < 2; ++hf) {
        if (hf) {                      // restage input half 1
            const float* src = input + (size_t)bb * EPB * SEQ_LEN + THALF;
            for (int idx = tid; idx < EPB * (THALF / 4); idx += 512) {
                int ee = idx / (THALF / 4);
                int cc = idx - ee * (THALF / 4);
                *(floatx4*)&sinl[ee * SP + 4 * cc] =
                    *(const floatx4*)(src + (size_t)ee * SEQ_LEN + 4 * cc);
            }
            __syncthreads();
        }
        for (int tl = 0; tl < THALF; ++tl) {
            const int t = hf * THALF + tl;
            // phase 1: A reads+MFMAs step t, B finishes step t
            if (team == 0) P0(); else P1(tl, t);
            __syncthreads();
            // phase 2: A finishes step t, B reads+MFMAs step t+1
            if (team == 0) P1(tl, t); else if (t + 1 < SEQ_LEN) P0();
            __syncthreads();
        }
    }
    #undef P0
    #undef P1

    // ---- epilogue: gather x (f32, overlay on sinl), project to classes ----
    float* xsh = sinl;                 // loop ended with __syncthreads
    {
        floatx4 xv;
        xv[0] = x01[0]; xv[1] = x01[1]; xv[2] = x23[0]; xv[3] = x23[1];
        *(floatx4*)&xsh[Eloc * 100 + 16 * ww + 4 * h] = xv;
        if (!duty) {                   // shared rows (skip 94,95)
            f2 xw = xs;
            *(f2*)&xsh[Eloc * 100 + 16 * S + 4 * h + 2 * p] = xw;
        }
    }
    __syncthreads();

    if (tid < EPB * OUT_CLASSES) {
        const int ee = tid / OUT_CLASSES;
        const int c  = tid - ee * OUT_CLASSES;
        float acc = b_ro[c];
        #pragma unroll 2
        for (int r = 0; r < NUM_NODES; ++r)
            acc += xsh[ee * 100 + r] * w_ro[c * NUM_NODES + r];
        out[((size_t)bb * EPB + ee) * OUT_CLASSES + c] = acc;
    }
}

extern "C" void kernel_launch(void* const* d_in, const int* in_sizes, int n_in,
                              void* d_out, int out_size, void* d_ws, size_t ws_size,
                              hipStream_t stream) {
    const float* input = (const float*)d_in[0];
    const float* w_ih  = (const float*)d_in[1];
    const float* b_ih  = (const float*)d_in[2];
    const float* w_hh  = (const float*)d_in[3];
    const float* b_hh  = (const float*)d_in[4];
    const float* w_ro  = (const float*)d_in[5];
    const float* b_ro  = (const float*)d_in[6];
    float* out = (float*)d_out;

    const int batch = in_sizes[0] / SEQ_LEN;   // 1024
    dim3 grid(batch / EPB);                    // 32 blocks, 2 chains each
    dim3 block(512);                           // 8 waves: 2 per SIMD, opposite phase

    hipLaunchKernelGGL(horn_kernel, grid, block, 0, stream,
                       input, w_ih, b_ih, w_hh, b_hh, w_ro, b_ro, out);
}